// Round 3
// baseline (813.486 us; speedup 1.0000x reference)
//
#include <hip/hip_runtime.h>

#define BB 256
#define SS 2048
#define TT 64

typedef float v4f __attribute__((ext_vector_type(4)));

__device__ __forceinline__ float fast_rcp(float x) {
#if __has_builtin(__builtin_amdgcn_rcpf)
  return __builtin_amdgcn_rcpf(x);
#else
  return 1.0f / x;
#endif
}

__device__ __forceinline__ float wave_max64(float v) {
#pragma unroll
  for (int m = 1; m < 64; m <<= 1) v = fmaxf(v, __shfl_xor(v, m, 64));
  return v;
}
__device__ __forceinline__ float wave_sum64(float v) {
#pragma unroll
  for (int m = 1; m < 64; m <<= 1) v += __shfl_xor(v, m, 64);
  return v;
}

// Mask dtype probe: uint8 all-ones -> 256 nonzero bytes; int32 -> 64; f32 -> 128.
// flag=1 means "byte-addressed (uint8)", else element-stride-4 with !=0 test.
__global__ void detect_mask(const unsigned char* __restrict__ m8, int* __restrict__ flag) {
  int cnt = 0;
  for (int i = 0; i < 256; ++i) cnt += (m8[i] != 0);
  *flag = (cnt > 192) ? 1 : 0;
}

// ---------------------------------------------------------------------------
// One block = one wave = one batch chain. Lane j owns state j.
// Scaled-exp domain: alpha[j] = M + log(s[j]);
//   s'[j] = (sum_i s[i] * E[i][j]) * exp(emit[j]),  E = exp(trans)
// Renormalize (wave max -> M, s/=mx) every 4 steps. Numerator fused.
// Matvec: s broadcast via LDS (same-address ds_read_b128 = conflict-free
// broadcast), E columns held in 16 float4 registers per lane.
// ---------------------------------------------------------------------------
__global__ __launch_bounds__(64, 1) void crf_fwd(
    const float* __restrict__ inputs,        // [B,S,T]
    const int* __restrict__ tags,            // [B,S]
    const unsigned char* __restrict__ mask8, // [B,S] (if flag==1)
    const int* __restrict__ mask32,          // [B,S] (if flag==0)
    const float* __restrict__ trans,         // [T,T] log-domain
    const float* __restrict__ start_t,       // [T]
    const float* __restrict__ end_t,         // [T]
    const int* __restrict__ flagp,
    float* __restrict__ out_per_b)           // [B]
{
  const int b = blockIdx.x;
  const int j = threadIdx.x;  // 0..63
  const int flag8 = *flagp;

  __shared__ __align__(16) float s_lds[TT];
  __shared__ __align__(16) int combo_s[SS];  // combo_s[t-1] = tag[t] | (mask[t]<<8)
  __shared__ float trans_s[TT * TT];         // log-domain transitions (numerator)

  const int* tagp = tags + (size_t)b * SS;
  const unsigned char* mp8 = mask8 + (size_t)b * SS;
  const int* mp32 = mask32 + (size_t)b * SS;

#pragma unroll 4
  for (int k = 0; k < SS / 64; ++k) {
    int idx = k * 64 + j;  // step t = idx+1
    int v = 0;
    if (idx < SS - 1) {
      int t = idx + 1;
      int mm = flag8 ? (int)(mp8[t] != 0) : (int)(mp32[t] != 0);
      v = (tagp[t] & 63) | (mm << 8);
    }
    combo_s[idx] = v;
  }
#pragma unroll 8
  for (int k = 0; k < TT; ++k) trans_s[k * 64 + j] = trans[k * 64 + j];
  __syncthreads();

  // E columns: E4[k][e] = exp(trans[4k+e][j])
  v4f E4[16];
#pragma unroll
  for (int k = 0; k < 16; ++k) {
    v4f e;
    e.x = __expf(trans[(4 * k + 0) * TT + j]);
    e.y = __expf(trans[(4 * k + 1) * TT + j]);
    e.z = __expf(trans[(4 * k + 2) * TT + j]);
    e.w = __expf(trans[(4 * k + 3) * TT + j]);
    E4[k] = e;
  }

  // ---- t = 0 init ----
  const float* eb = inputs + (size_t)b * SS * TT;
  const float* ep = eb + j;
  float emit0 = ep[0];
  float alpha0 = start_t[j] + emit0;
  float Mw = wave_max64(alpha0);
  double M = (double)Mw;
  float s = __expf(alpha0 - Mw);

  int tag0 = tagp[0];
  float mf0 = flag8 ? (float)(mp8[0] != 0) : (float)(mp32[0] != 0);
  float numU = start_t[tag0];                     // uniform accumulator
  float numL = (j == tag0) ? emit0 * mf0 : 0.0f;  // per-lane emit gathers
  float cnt = mf0;
  int tag_prev = tag0;

#define DO_STEP(E_, TRV_, TG_, MF_, EOKF_, REN_) do {                       \
    if (REN_) {                                                             \
      float _mx = wave_max64(s);                                            \
      M += (double)__logf(_mx);                                             \
      s *= fast_rcp(_mx);                                                   \
    }                                                                       \
    s_lds[j] = s;                                                           \
    const v4f* __restrict__ _sp = (const v4f*)s_lds;                        \
    v4f _a0 = {0.f,0.f,0.f,0.f}, _a1 = {0.f,0.f,0.f,0.f};                   \
    v4f _a2 = {0.f,0.f,0.f,0.f}, _a3 = {0.f,0.f,0.f,0.f};                   \
    _Pragma("unroll")                                                       \
    for (int _i = 0; _i < 4; ++_i) {                                        \
      _a0 += _sp[4 * _i + 0] * E4[4 * _i + 0];                              \
      _a1 += _sp[4 * _i + 1] * E4[4 * _i + 1];                              \
      _a2 += _sp[4 * _i + 2] * E4[4 * _i + 2];                              \
      _a3 += _sp[4 * _i + 3] * E4[4 * _i + 3];                              \
    }                                                                       \
    v4f _aa = (_a0 + _a1) + (_a2 + _a3);                                    \
    float _dot = (_aa.x + _aa.y) + (_aa.z + _aa.w);                         \
    float _snew = _dot * __expf(E_);                                        \
    s = (MF_ != 0.0f) ? _snew : s;                                          \
    numU += TRV_ * MF_;                                                     \
    numL += ((j == (TG_)) ? E_ : 0.0f) * (MF_ * (EOKF_));                   \
    cnt += MF_;                                                             \
  } while (0)

#define LOAD8(D0, D1, D2, D3, D4, D5, D6, D7, TB_) do {                     \
    int _tb = (TB_);                                                        \
    int _t0 = _tb + 0 < SS - 1 ? _tb + 0 : SS - 1;                          \
    int _t1 = _tb + 1 < SS - 1 ? _tb + 1 : SS - 1;                          \
    int _t2 = _tb + 2 < SS - 1 ? _tb + 2 : SS - 1;                          \
    int _t3 = _tb + 3 < SS - 1 ? _tb + 3 : SS - 1;                          \
    int _t4 = _tb + 4 < SS - 1 ? _tb + 4 : SS - 1;                          \
    int _t5 = _tb + 5 < SS - 1 ? _tb + 5 : SS - 1;                          \
    int _t6 = _tb + 6 < SS - 1 ? _tb + 6 : SS - 1;                          \
    int _t7 = _tb + 7 < SS - 1 ? _tb + 7 : SS - 1;                          \
    D0 = ep[(size_t)_t0 * TT]; D1 = ep[(size_t)_t1 * TT];                   \
    D2 = ep[(size_t)_t2 * TT]; D3 = ep[(size_t)_t3 * TT];                   \
    D4 = ep[(size_t)_t4 * TT]; D5 = ep[(size_t)_t5 * TT];                   \
    D6 = ep[(size_t)_t6 * TT]; D7 = ep[(size_t)_t7 * TT];                   \
  } while (0)

  // 8 steps per BLOCK8; the final block's last step (t=2048) is a padded
  // no-op: combo_s[2047]=0 -> mask=0 -> s frozen, numerator terms *0.
#define BLOCK8(CB_, E0, E1, E2, E3, E4_, E5, E6, E7, T0_) do {              \
    int4 _ca = *(const int4*)&combo_s[(CB_)];                               \
    int4 _cb = *(const int4*)&combo_s[(CB_) + 4];                           \
    int _tg0 = _ca.x & 63, _tg1 = _ca.y & 63;                               \
    int _tg2 = _ca.z & 63, _tg3 = _ca.w & 63;                               \
    int _tg4 = _cb.x & 63, _tg5 = _cb.y & 63;                               \
    int _tg6 = _cb.z & 63, _tg7 = _cb.w & 63;                               \
    float _m0 = (_ca.x >> 8) ? 1.0f : 0.0f;                                 \
    float _m1 = (_ca.y >> 8) ? 1.0f : 0.0f;                                 \
    float _m2 = (_ca.z >> 8) ? 1.0f : 0.0f;                                 \
    float _m3 = (_ca.w >> 8) ? 1.0f : 0.0f;                                 \
    float _m4 = (_cb.x >> 8) ? 1.0f : 0.0f;                                 \
    float _m5 = (_cb.y >> 8) ? 1.0f : 0.0f;                                 \
    float _m6 = (_cb.z >> 8) ? 1.0f : 0.0f;                                 \
    float _m7 = (_cb.w >> 8) ? 1.0f : 0.0f;                                 \
    float _tv0 = trans_s[tag_prev * TT + _tg0];                             \
    float _tv1 = trans_s[_tg0 * TT + _tg1];                                 \
    float _tv2 = trans_s[_tg1 * TT + _tg2];                                 \
    float _tv3 = trans_s[_tg2 * TT + _tg3];                                 \
    float _tv4 = trans_s[_tg3 * TT + _tg4];                                 \
    float _tv5 = trans_s[_tg4 * TT + _tg5];                                 \
    float _tv6 = trans_s[_tg5 * TT + _tg6];                                 \
    float _tv7 = trans_s[_tg6 * TT + _tg7];                                 \
    tag_prev = _tg7;                                                        \
    float _e0 = ((T0_) + 0 <= SS - 2) ? 1.0f : 0.0f;                        \
    float _e1 = ((T0_) + 1 <= SS - 2) ? 1.0f : 0.0f;                        \
    float _e2 = ((T0_) + 2 <= SS - 2) ? 1.0f : 0.0f;                        \
    float _e3 = ((T0_) + 3 <= SS - 2) ? 1.0f : 0.0f;                        \
    float _e4 = ((T0_) + 4 <= SS - 2) ? 1.0f : 0.0f;                        \
    float _e5 = ((T0_) + 5 <= SS - 2) ? 1.0f : 0.0f;                        \
    float _e6 = ((T0_) + 6 <= SS - 2) ? 1.0f : 0.0f;                        \
    float _e7 = ((T0_) + 7 <= SS - 2) ? 1.0f : 0.0f;                        \
    DO_STEP(E0, _tv0, _tg0, _m0, _e0, true);                                \
    DO_STEP(E1, _tv1, _tg1, _m1, _e1, false);                               \
    DO_STEP(E2, _tv2, _tg2, _m2, _e2, false);                               \
    DO_STEP(E3, _tv3, _tg3, _m3, _e3, false);                               \
    DO_STEP(E4_, _tv4, _tg4, _m4, _e4, true);                               \
    DO_STEP(E5, _tv5, _tg5, _m5, _e5, false);                               \
    DO_STEP(E6, _tv6, _tg6, _m6, _e6, false);                               \
    DO_STEP(E7, _tv7, _tg7, _m7, _e7, false);                               \
  } while (0)

  float eA0, eA1, eA2, eA3, eA4, eA5, eA6, eA7;
  float eB0, eB1, eB2, eB3, eB4, eB5, eB6, eB7;
  LOAD8(eA0, eA1, eA2, eA3, eA4, eA5, eA6, eA7, 1);

#pragma unroll 1
  for (int blk = 0; blk < SS / 16; ++blk) {
    const int t0 = 16 * blk + 1;
    LOAD8(eB0, eB1, eB2, eB3, eB4, eB5, eB6, eB7, t0 + 8);
    BLOCK8(16 * blk, eA0, eA1, eA2, eA3, eA4, eA5, eA6, eA7, t0);
    LOAD8(eA0, eA1, eA2, eA3, eA4, eA5, eA6, eA7, t0 + 16);
    BLOCK8(16 * blk + 8, eB0, eB1, eB2, eB3, eB4, eB5, eB6, eB7, t0 + 8);
  }

  // ---- denominator: logsumexp(alpha + end) ----
  float term = s * __expf(end_t[j]);
  float tot = wave_sum64(term);
  float den = (float)(M + (double)__logf(tot));

  // ---- numerator finish ----
  float numSum = wave_sum64(numL);
  if (j == 0) {
    int last_idx = (int)(cnt + 0.5f) - 1;  // mask.sum() - 1
    int lt = tagp[last_idx];
    float mf_last = flag8 ? (float)(mp8[SS - 1] != 0) : (float)(mp32[SS - 1] != 0);
    float last_in = eb[(size_t)(SS - 1) * TT + lt];
    float num = numU + numSum + end_t[lt] + last_in * mf_last;
    out_per_b[b] = num - den;
  }
}

// Sum 256 per-batch values in double, write fp32 scalar.
__global__ __launch_bounds__(64) void final_reduce(const float* __restrict__ per_b,
                                                   float* __restrict__ out) {
  int j = threadIdx.x;
  double acc = 0.0;
#pragma unroll
  for (int k = 0; k < BB / 64; ++k) acc += (double)per_b[k * 64 + j];
#pragma unroll
  for (int m = 1; m < 64; m <<= 1) acc += __shfl_xor(acc, m, 64);
  if (j == 0) out[0] = (float)acc;
}

extern "C" void kernel_launch(void* const* d_in, const int* in_sizes, int n_in,
                              void* d_out, int out_size, void* d_ws, size_t ws_size,
                              hipStream_t stream) {
  const float* inputs = (const float*)d_in[0];
  const int* tags = (const int*)d_in[1];
  const unsigned char* mask8 = (const unsigned char*)d_in[2];
  const int* mask32 = (const int*)d_in[2];
  const float* trans = (const float*)d_in[3];
  const float* start_t = (const float*)d_in[4];
  const float* end_t = (const float*)d_in[5];

  int* flag = (int*)d_ws;                          // 1 int
  float* per_b = (float*)((char*)d_ws + 256);      // 256 floats

  detect_mask<<<dim3(1), dim3(1), 0, stream>>>(mask8, flag);
  crf_fwd<<<dim3(BB), dim3(64), 0, stream>>>(inputs, tags, mask8, mask32, trans,
                                             start_t, end_t, flag, per_b);
  final_reduce<<<dim3(1), dim3(64), 0, stream>>>(per_b, (float*)d_out);
}

// Round 4
// 529.443 us; speedup vs baseline: 1.5365x; 1.5365x over previous
//
#include <hip/hip_runtime.h>

#define BB 256
#define SS 2048
#define TT 64

typedef float v2f __attribute__((ext_vector_type(2)));

__device__ __forceinline__ int f2i(float x) { return __float_as_int(x); }
__device__ __forceinline__ float i2f(int x) { return __int_as_float(x); }

// DPP controls
#define DPP_XOR1 0xB1    // quad_perm [1,0,3,2]
#define DPP_XOR2 0x4E    // quad_perm [2,3,0,1]
#define DPP_XOR7 0x141   // row_half_mirror (l -> l^7 within 8-lane halves)
#define DPP_ROR8 0x128   // row_ror:8 == l -> l^8 within 16-lane rows
template <int CTRL>
__device__ __forceinline__ float dppf(float x) {
  return i2f(__builtin_amdgcn_update_dpp(0, f2i(x), CTRL, 0xF, 0xF, false));
}
// gfx950 half-wave / row-pair swaps (VALU-rate cross-lane).
__device__ __forceinline__ void pl16_swap(float& a, float& b) {
  asm("v_permlane16_swap_b32 %0, %1" : "+v"(a), "+v"(b));
}
__device__ __forceinline__ void pl32_swap(float& a, float& b) {
  asm("v_permlane32_swap_b32 %0, %1" : "+v"(a), "+v"(b));
}

__device__ __forceinline__ float fast_rcp(float x) {
#if __has_builtin(__builtin_amdgcn_rcpf)
  return __builtin_amdgcn_rcpf(x);
#else
  return 1.0f / x;
#endif
}

__device__ __forceinline__ float wave_max64(float v) {
#pragma unroll
  for (int m = 1; m < 64; m <<= 1) v = fmaxf(v, __shfl_xor(v, m, 64));
  return v;
}
__device__ __forceinline__ float wave_sum64(float v) {
#pragma unroll
  for (int m = 1; m < 64; m <<= 1) v += __shfl_xor(v, m, 64);
  return v;
}

// Duplicate s over lane-bits {5,4,3}: each lane ends with the 8 values
// { s_i : i == lane (mod 8) } in fixed registers (source order probed at init).
__device__ __forceinline__ void gather8(float s, float v[8]) {
  float x0 = s, x1 = s;
  pl32_swap(x0, x1);              // bit-5 variants
  float y0 = x0, y1 = x0, y2 = x1, y3 = x1;
  pl16_swap(y0, y1);              // bit-4 variants
  pl16_swap(y2, y3);
  v[0] = y0; v[1] = dppf<DPP_ROR8>(y0);   // bit-3 variants
  v[2] = y1; v[3] = dppf<DPP_ROR8>(y1);
  v[4] = y2; v[5] = dppf<DPP_ROR8>(y2);
  v[6] = y3; v[7] = dppf<DPP_ROR8>(y3);
}

// Mask dtype probe: uint8 all-ones -> 64 nonzero bytes in first 64; int32 -> 16.
__global__ __launch_bounds__(64) void detect_mask(const unsigned char* __restrict__ m8,
                                                  int* __restrict__ flag) {
  int j = threadIdx.x;
  unsigned long long bal = __ballot(m8[j] != 0);
  if (j == 0) *flag = (__popcll(bal) > 48) ? 1 : 0;
}

// ---------------------------------------------------------------------------
// One block = one wave = one batch chain. Lane j owns state j.
// Scaled-exp domain: alpha[j] = M + log(s[j]);
//   s'[j] = (sum_i s[i] * E[i][j]) * exp(emit[j]),  E = exp(trans)
// Matvec fully in VALU: butterfly gather (permlane/DPP) -> 8 partial dots
// (v_pk_fma) -> reduce-scatter folds {7,2,1} (all DPP). No DS ops on the
// critical chain. Renorm every 4 steps via DPP max, applied to the output.
// ---------------------------------------------------------------------------
__global__ __launch_bounds__(64, 1) void crf_fwd(
    const float* __restrict__ inputs,        // [B,S,T]
    const int* __restrict__ tags,            // [B,S]
    const unsigned char* __restrict__ mask8, // [B,S] (if flag==1)
    const int* __restrict__ mask32,          // [B,S] (if flag==0)
    const float* __restrict__ trans,         // [T,T] log-domain
    const float* __restrict__ start_t,       // [T]
    const float* __restrict__ end_t,         // [T]
    const int* __restrict__ flagp,
    float* __restrict__ out_per_b)           // [B]
{
  const int b = blockIdx.x;
  const int j = threadIdx.x;  // 0..63
  const int c = j & 7;
  const int flag8 = *flagp;

  __shared__ __align__(16) int combo_s[SS];  // combo_s[t-1] = tag[t] | (mask[t]<<8)
  __shared__ float trans_s[TT * TT];         // log-domain transitions (numerator)

  const int* tagp = tags + (size_t)b * SS;
  const unsigned char* mp8 = mask8 + (size_t)b * SS;
  const int* mp32 = mask32 + (size_t)b * SS;

#pragma unroll 4
  for (int k = 0; k < SS / 64; ++k) {
    int idx = k * 64 + j;  // step t = idx+1
    int v = 0;
    if (idx < SS - 1) {
      int t = idx + 1;
      int mm = flag8 ? (int)(mp8[t] != 0) : (int)(mp32[t] != 0);
      v = (tagp[t] & 63) | (mm << 8);
    }
    combo_s[idx] = v;
  }
#pragma unroll 8
  for (int k = 0; k < TT; ++k) trans_s[k * 64 + j] = trans[k * 64 + j];
  __syncthreads();

  // Probe the gather network once to learn each register's source lane,
  // then bake E-fragments accordingly (robust to permlane operand order).
  // F2[m][kk] = { E[i_m][(j&~7)|((2kk)^c)], E[i_m][(j&~7)|((2kk+1)^c)] }
  v2f F2[8][4];
  {
    float pv[8];
    gather8((float)j, pv);
#pragma unroll
    for (int m = 0; m < 8; ++m) {
      const int im = (int)pv[m];
      const float* tr = trans + im * TT + (j & ~7);
#pragma unroll
      for (int kk = 0; kk < 4; ++kk) {
        v2f e;
        e.x = __expf(tr[(2 * kk) ^ c]);
        e.y = __expf(tr[(2 * kk + 1) ^ c]);
        F2[m][kk] = e;
      }
    }
  }

  // ---- t = 0 init ----
  const float* eb = inputs + (size_t)b * SS * TT;
  const float* ep = eb + j;
  float emit0 = ep[0];
  float alpha0 = start_t[j] + emit0;
  float Mw = wave_max64(alpha0);
  double M = (double)Mw;
  float s = __expf(alpha0 - Mw);

  int tag0 = tagp[0];
  float mf0 = flag8 ? (float)(mp8[0] != 0) : (float)(mp32[0] != 0);
  float numU = start_t[tag0];                     // uniform accumulator
  float numL = (j == tag0) ? emit0 * mf0 : 0.0f;  // per-lane emit gathers
  float cnt = mf0;
  int tag_prev = tag0;

#define DO_STEP(E_, TRV_, TG_, MF_, EOKF_, REN_) do {                       \
    float _v[8];                                                            \
    gather8(s, _v);                                                         \
    float _rsc = 1.0f;                                                      \
    if (REN_) { /* global max of all 64 s: local 8 + folds {7,2,1} */       \
      float _a = fmaxf(fmaxf(_v[0], _v[1]), fmaxf(_v[2], _v[3]));           \
      float _bm = fmaxf(fmaxf(_v[4], _v[5]), fmaxf(_v[6], _v[7]));          \
      float _mx = fmaxf(_a, _bm);                                           \
      _mx = fmaxf(_mx, dppf<DPP_XOR7>(_mx));                                \
      _mx = fmaxf(_mx, dppf<DPP_XOR2>(_mx));                                \
      _mx = fmaxf(_mx, dppf<DPP_XOR1>(_mx));                                \
      _rsc = fast_rcp(_mx);                                                 \
      M += (double)__logf(_mx);                                             \
    }                                                                       \
    v2f _Q0, _Q1, _Q2, _Q3;                                                 \
    { v2f _d = {_v[0], _v[0]};                                              \
      _Q0 = _d * F2[0][0]; _Q1 = _d * F2[0][1];                             \
      _Q2 = _d * F2[0][2]; _Q3 = _d * F2[0][3]; }                           \
    _Pragma("unroll")                                                       \
    for (int _m = 1; _m < 8; ++_m) {                                        \
      v2f _d = {_v[_m], _v[_m]};                                            \
      _Q0 += _d * F2[_m][0]; _Q1 += _d * F2[_m][1];                         \
      _Q2 += _d * F2[_m][2]; _Q3 += _d * F2[_m][3];                         \
    }                                                                       \
    float _p0 = _Q0.x, _p1 = _Q0.y, _p2 = _Q1.x, _p3 = _Q1.y;               \
    float _p4 = _Q2.x, _p5 = _Q2.y, _p6 = _Q3.x, _p7 = _Q3.y;               \
    _p0 += dppf<DPP_XOR7>(_p7); _p1 += dppf<DPP_XOR7>(_p6);                 \
    _p2 += dppf<DPP_XOR7>(_p5); _p3 += dppf<DPP_XOR7>(_p4);                 \
    _p0 += dppf<DPP_XOR2>(_p2); _p1 += dppf<DPP_XOR2>(_p3);                 \
    _p0 += dppf<DPP_XOR1>(_p1);                                             \
    float _ex = __expf(E_) * _rsc;                                          \
    float _snew = _p0 * _ex;                                                \
    float _sold = (REN_) ? s * _rsc : s;                                    \
    s = (MF_ != 0.0f) ? _snew : _sold;                                      \
    numU += TRV_ * MF_;                                                     \
    numL += ((j == (TG_)) ? E_ : 0.0f) * (MF_ * (EOKF_));                   \
    cnt += MF_;                                                             \
  } while (0)

#define LOAD8(D0, D1, D2, D3, D4, D5, D6, D7, TB_) do {                     \
    int _tb = (TB_);                                                        \
    int _t0 = _tb + 0 < SS - 1 ? _tb + 0 : SS - 1;                          \
    int _t1 = _tb + 1 < SS - 1 ? _tb + 1 : SS - 1;                          \
    int _t2 = _tb + 2 < SS - 1 ? _tb + 2 : SS - 1;                          \
    int _t3 = _tb + 3 < SS - 1 ? _tb + 3 : SS - 1;                          \
    int _t4 = _tb + 4 < SS - 1 ? _tb + 4 : SS - 1;                          \
    int _t5 = _tb + 5 < SS - 1 ? _tb + 5 : SS - 1;                          \
    int _t6 = _tb + 6 < SS - 1 ? _tb + 6 : SS - 1;                          \
    int _t7 = _tb + 7 < SS - 1 ? _tb + 7 : SS - 1;                          \
    D0 = ep[(size_t)_t0 * TT]; D1 = ep[(size_t)_t1 * TT];                   \
    D2 = ep[(size_t)_t2 * TT]; D3 = ep[(size_t)_t3 * TT];                   \
    D4 = ep[(size_t)_t4 * TT]; D5 = ep[(size_t)_t5 * TT];                   \
    D6 = ep[(size_t)_t6 * TT]; D7 = ep[(size_t)_t7 * TT];                   \
  } while (0)

  // 8 steps per BLOCK8; final block's last step (t=2048) is a padded no-op:
  // combo_s[2047]=0 -> mask=0 -> s frozen, numerator terms *0.
#define BLOCK8(CB_, E0, E1, E2, E3, E4_, E5, E6, E7, T0_) do {              \
    int4 _ca = *(const int4*)&combo_s[(CB_)];                               \
    int4 _cb = *(const int4*)&combo_s[(CB_) + 4];                           \
    int _tg0 = _ca.x & 63, _tg1 = _ca.y & 63;                               \
    int _tg2 = _ca.z & 63, _tg3 = _ca.w & 63;                               \
    int _tg4 = _cb.x & 63, _tg5 = _cb.y & 63;                               \
    int _tg6 = _cb.z & 63, _tg7 = _cb.w & 63;                               \
    float _m0 = (_ca.x >> 8) ? 1.0f : 0.0f;                                 \
    float _m1 = (_ca.y >> 8) ? 1.0f : 0.0f;                                 \
    float _m2 = (_ca.z >> 8) ? 1.0f : 0.0f;                                 \
    float _m3 = (_ca.w >> 8) ? 1.0f : 0.0f;                                 \
    float _m4 = (_cb.x >> 8) ? 1.0f : 0.0f;                                 \
    float _m5 = (_cb.y >> 8) ? 1.0f : 0.0f;                                 \
    float _m6 = (_cb.z >> 8) ? 1.0f : 0.0f;                                 \
    float _m7 = (_cb.w >> 8) ? 1.0f : 0.0f;                                 \
    float _tv0 = trans_s[tag_prev * TT + _tg0];                             \
    float _tv1 = trans_s[_tg0 * TT + _tg1];                                 \
    float _tv2 = trans_s[_tg1 * TT + _tg2];                                 \
    float _tv3 = trans_s[_tg2 * TT + _tg3];                                 \
    float _tv4 = trans_s[_tg3 * TT + _tg4];                                 \
    float _tv5 = trans_s[_tg4 * TT + _tg5];                                 \
    float _tv6 = trans_s[_tg5 * TT + _tg6];                                 \
    float _tv7 = trans_s[_tg6 * TT + _tg7];                                 \
    tag_prev = _tg7;                                                        \
    float _e0 = ((T0_) + 0 <= SS - 2) ? 1.0f : 0.0f;                        \
    float _e1 = ((T0_) + 1 <= SS - 2) ? 1.0f : 0.0f;                        \
    float _e2 = ((T0_) + 2 <= SS - 2) ? 1.0f : 0.0f;                        \
    float _e3 = ((T0_) + 3 <= SS - 2) ? 1.0f : 0.0f;                        \
    float _e4 = ((T0_) + 4 <= SS - 2) ? 1.0f : 0.0f;                        \
    float _e5 = ((T0_) + 5 <= SS - 2) ? 1.0f : 0.0f;                        \
    float _e6 = ((T0_) + 6 <= SS - 2) ? 1.0f : 0.0f;                        \
    float _e7 = ((T0_) + 7 <= SS - 2) ? 1.0f : 0.0f;                        \
    DO_STEP(E0, _tv0, _tg0, _m0, _e0, true);                                \
    DO_STEP(E1, _tv1, _tg1, _m1, _e1, false);                               \
    DO_STEP(E2, _tv2, _tg2, _m2, _e2, false);                               \
    DO_STEP(E3, _tv3, _tg3, _m3, _e3, false);                               \
    DO_STEP(E4_, _tv4, _tg4, _m4, _e4, true);                               \
    DO_STEP(E5, _tv5, _tg5, _m5, _e5, false);                               \
    DO_STEP(E6, _tv6, _tg6, _m6, _e6, false);                               \
    DO_STEP(E7, _tv7, _tg7, _m7, _e7, false);                               \
  } while (0)

  float eA0, eA1, eA2, eA3, eA4, eA5, eA6, eA7;
  float eB0, eB1, eB2, eB3, eB4, eB5, eB6, eB7;
  LOAD8(eA0, eA1, eA2, eA3, eA4, eA5, eA6, eA7, 1);

#pragma unroll 1
  for (int blk = 0; blk < SS / 16; ++blk) {
    const int t0 = 16 * blk + 1;
    LOAD8(eB0, eB1, eB2, eB3, eB4, eB5, eB6, eB7, t0 + 8);
    BLOCK8(16 * blk, eA0, eA1, eA2, eA3, eA4, eA5, eA6, eA7, t0);
    LOAD8(eA0, eA1, eA2, eA3, eA4, eA5, eA6, eA7, t0 + 16);
    BLOCK8(16 * blk + 8, eB0, eB1, eB2, eB3, eB4, eB5, eB6, eB7, t0 + 8);
  }

  // ---- denominator: logsumexp(alpha + end) ----
  float term = s * __expf(end_t[j]);
  float tot = wave_sum64(term);
  float den = (float)(M + (double)__logf(tot));

  // ---- numerator finish ----
  float numSum = wave_sum64(numL);
  if (j == 0) {
    int last_idx = (int)(cnt + 0.5f) - 1;  // mask.sum() - 1
    int lt = tagp[last_idx];
    float mf_last = flag8 ? (float)(mp8[SS - 1] != 0) : (float)(mp32[SS - 1] != 0);
    float last_in = eb[(size_t)(SS - 1) * TT + lt];
    float num = numU + numSum + end_t[lt] + last_in * mf_last;
    out_per_b[b] = num - den;
  }
}

// Sum 256 per-batch values in double, write fp32 scalar.
__global__ __launch_bounds__(64) void final_reduce(const float* __restrict__ per_b,
                                                   float* __restrict__ out) {
  int j = threadIdx.x;
  double acc = 0.0;
#pragma unroll
  for (int k = 0; k < BB / 64; ++k) acc += (double)per_b[k * 64 + j];
#pragma unroll
  for (int m = 1; m < 64; m <<= 1) acc += __shfl_xor(acc, m, 64);
  if (j == 0) out[0] = (float)acc;
}

extern "C" void kernel_launch(void* const* d_in, const int* in_sizes, int n_in,
                              void* d_out, int out_size, void* d_ws, size_t ws_size,
                              hipStream_t stream) {
  const float* inputs = (const float*)d_in[0];
  const int* tags = (const int*)d_in[1];
  const unsigned char* mask8 = (const unsigned char*)d_in[2];
  const int* mask32 = (const int*)d_in[2];
  const float* trans = (const float*)d_in[3];
  const float* start_t = (const float*)d_in[4];
  const float* end_t = (const float*)d_in[5];

  int* flag = (int*)d_ws;                      // 1 int
  float* per_b = (float*)((char*)d_ws + 256);  // 256 floats

  detect_mask<<<dim3(1), dim3(64), 0, stream>>>(mask8, flag);
  crf_fwd<<<dim3(BB), dim3(64), 0, stream>>>(inputs, tags, mask8, mask32, trans,
                                             start_t, end_t, flag, per_b);
  final_reduce<<<dim3(1), dim3(64), 0, stream>>>(per_b, (float*)d_out);
}